// Round 18
// baseline (234.093 us; speedup 1.0000x reference)
//
#include <hip/hip_runtime.h>
#include <hip/hip_bf16.h>
#include <hip/hip_fp16.h>
#include <math.h>

__device__ __forceinline__ float leaky02(float x) { return x > 0.f ? x : 0.2f * x; }

#define CPAD 32   // counters padded to one 128B line each (R16: fixed atomic serialization)

// K_prep: fat kernel. Blocks [0,NBc): edge dst count+rank (returning atomic
// on line-padded counters). Blocks [NBc,...): node1 transform.
__global__ void k_prep(const float* __restrict__ x, const float* __restrict__ W1,
                       const float* __restrict__ att_s, const float* __restrict__ att_d,
                       __half* __restrict__ h1h, float* __restrict__ as1,
                       float* __restrict__ ad1,
                       const int* __restrict__ ei, int* __restrict__ counts_pad,
                       int* __restrict__ epos,
                       int N, int E, int NBc) {
    int b = blockIdx.x;
    if (b < NBc) {
        int t = b * blockDim.x + threadIdx.x;
        if (t < E) {
            int d = ei[E + t];
            epos[t] = atomicAdd(&counts_pad[(size_t)d * CPAD], 1);
        }
        return;
    }
    int nb = b - NBc;
    int wid = threadIdx.x >> 6;
    int n = nb * 4 + wid;
    if (n >= N) return;
    int lane = threadIdx.x & 63;
    int c = lane * 4;
    float x0 = x[n * 3 + 0], x1 = x[n * 3 + 1], x2 = x[n * 3 + 2];
    float4 w0 = *reinterpret_cast<const float4*>(&W1[c]);
    float4 w1 = *reinterpret_cast<const float4*>(&W1[256 + c]);
    float4 w2 = *reinterpret_cast<const float4*>(&W1[512 + c]);
    float h0 = x0 * w0.x + x1 * w1.x + x2 * w2.x;
    float h1_ = x0 * w0.y + x1 * w1.y + x2 * w2.y;
    float h2_ = x0 * w0.z + x1 * w1.z + x2 * w2.z;
    float h3 = x0 * w0.w + x1 * w1.w + x2 * w2.w;
    union { __half2 h[2]; uint2 u; } pk;
    pk.h[0] = __floats2half2_rn(h0, h1_);
    pk.h[1] = __floats2half2_rn(h2_, h3);
    *reinterpret_cast<uint2*>(h1h + (size_t)n * 256 + c) = pk.u;
    float4 as = *reinterpret_cast<const float4*>(&att_s[c]);
    float4 ad = *reinterpret_cast<const float4*>(&att_d[c]);
    float vs = h0 * as.x + h1_ * as.y + h2_ * as.z + h3 * as.w;
    float vd = h0 * ad.x + h1_ * ad.y + h2_ * ad.z + h3 * ad.w;
    #pragma unroll
    for (int m = 1; m < 8; m <<= 1) {
        vs += __shfl_xor(vs, m);
        vd += __shfl_xor(vd, m);
    }
    if ((lane & 7) == 0) {
        as1[n * 8 + (lane >> 3)] = vs;
        ad1[n * 8 + (lane >> 3)] = vd;
    }
}

// K_compact: densify padded counters (one thread per node).
__global__ void k_compact(const int* __restrict__ counts_pad,
                          int* __restrict__ counts, int N) {
    int i = blockIdx.x * blockDim.x + threadIdx.x;
    if (i < N) counts[i] = counts_pad[(size_t)i * CPAD];
}

// K_offs2: per-block offsets; block computes its own prefix (dense counts).
// Also places the self-loop at the LAST slot of each segment.
__global__ void k_offs2(const int* __restrict__ counts,
                        int* __restrict__ offs, int* __restrict__ srcs, int N) {
    __shared__ int red[4];
    __shared__ int wsum[4];
    int b = blockIdx.x;
    int t = threadIdx.x;
    int lane = t & 63, wid = t >> 6;
    int lim = b << 10;
    int s = 0;
    for (int i = t * 4; i < lim; i += 1024) {
        int4 v = *reinterpret_cast<const int4*>(&counts[i]);
        s += v.x + v.y + v.z + v.w + 4;
    }
    #pragma unroll
    for (int m = 1; m < 64; m <<= 1) s += __shfl_xor(s, m);
    if (lane == 0) red[wid] = s;
    __syncthreads();
    int P = red[0] + red[1] + red[2] + red[3];
    int i0 = (b << 10) + t * 4;
    int c0 = 0, c1 = 0, c2 = 0, c3 = 0;
    if (i0 + 3 < N) {
        int4 cv = *reinterpret_cast<const int4*>(&counts[i0]);
        c0 = cv.x + 1; c1 = cv.y + 1; c2 = cv.z + 1; c3 = cv.w + 1;
    } else {
        if (i0 + 0 < N) c0 = counts[i0 + 0] + 1;
        if (i0 + 1 < N) c1 = counts[i0 + 1] + 1;
        if (i0 + 2 < N) c2 = counts[i0 + 2] + 1;
        if (i0 + 3 < N) c3 = counts[i0 + 3] + 1;
    }
    int tsum = c0 + c1 + c2 + c3;
    int incl = tsum;
    #pragma unroll
    for (int off = 1; off < 64; off <<= 1) {
        int tv = __shfl_up(incl, off);
        if (lane >= off) incl += tv;
    }
    if (lane == 63) wsum[wid] = incl;
    __syncthreads();
    int woff = 0;
    for (int w = 0; w < wid; ++w) woff += wsum[w];
    int base = P + woff + incl - tsum;
    int p0 = base;
    int p1 = p0 + c0;
    int p2 = p1 + c1;
    int p3 = p2 + c2;
    int p4 = p3 + c3;
    if (i0 + 0 < N) { offs[i0 + 1] = p1; srcs[p1 - 1] = i0 + 0; }
    if (i0 + 1 < N) { offs[i0 + 2] = p2; srcs[p2 - 1] = i0 + 1; }
    if (i0 + 2 < N) { offs[i0 + 3] = p3; srcs[p3 - 1] = i0 + 2; }
    if (i0 + 3 < N) { offs[i0 + 4] = p4; srcs[p4 - 1] = i0 + 3; }
    if (b == 0 && t == 0) offs[0] = 0;
}

// K_scatter: E edges only; position precomputed (epos); no atomics.
__global__ void k_scatter(const int* __restrict__ ei, const int* __restrict__ offs,
                          const int* __restrict__ epos, int* __restrict__ srcs, int E) {
    int t = blockIdx.x * blockDim.x + threadIdx.x;
    if (t < E) {
        int s = ei[t], d = ei[E + t];
        srcs[offs[d] + epos[t]] = s;
    }
}

// K_agg1n2: agg1 + node2 tail via LDS.
// Inner loop: TWO named 8-batches per iteration (rawA/rawB) -> 16 gather
// loads in flight per wave (R15's 8-deep raised BW 2.68->3.39 TB/s at only
// VGPR 32; compiler consumes raws as they land so reg cost stays low).
// Fast path kb+16<=cnt is predication-free; ragged tail uses the
// predicated batch-8 (p=0 pad, exact). All arrays statically indexed
// (rule 20); all shfls unconditional (convergent).
// W2 staging dst-linear (conflict-free, R13); feat_lds linear (R12);
// LDS 20480 B = exactly 8 blocks/CU (R11); launch_bounds caps VGPR (R5/R7).
__global__ void __launch_bounds__(256, 8)
k_agg1n2(const __half* __restrict__ h1h, const float* __restrict__ as1,
         const float* __restrict__ ad1, const float* __restrict__ b1,
         const float* __restrict__ W2, const float* __restrict__ att_s2,
         const float* __restrict__ att_d2,
         const int* __restrict__ offs, const int* __restrict__ srcs,
         __half* __restrict__ h2h, float* __restrict__ as2,
         float* __restrict__ ad2, int N) {
    __shared__ float w_lds[4096];
    __shared__ float feat_lds[1024];
    int t = threadIdx.x;
    #pragma unroll
    for (int p = 0; p < 4; ++p) {
        int dw = p * 1024 + t * 4;
        int hi = dw >> 11;
        int r = dw & 2047;
        int row = r >> 5;
        int rem = r & 31;
        int half = rem >> 4;
        int o = rem & 15;
        int k = (hi << 7) | (half << 6) | row;
        *reinterpret_cast<float4*>(&w_lds[dw]) =
            *reinterpret_cast<const float4*>(&W2[k * 16 + o]);
    }
    __syncthreads();

    int wid = t >> 6;
    int d = blockIdx.x * 4 + wid;
    if (d >= N) return;
    int lane = t & 63;
    int head = lane >> 3;
    int po = lane >> 3;
    int ph = lane & 7;
    float ad_p = ad1[d * 8 + ph];
    int beg = offs[d], end = offs[d + 1];
    float denom = 0.f, a0 = 0.f, a1 = 0.f, a2 = 0.f, a3 = 0.f;
    for (int cb = beg; cb < end; cb += 64) {
        int idx = cb + lane;
        int myS = srcs[idx < end ? idx : end - 1];
        int cnt = min(64, end - cb);   // wave-uniform
        float p8[8];
        #pragma unroll
        for (int j = 0; j < 8; ++j) {
            int s = __shfl(myS, po * 8 + j);
            p8[j] = __expf(leaky02(as1[s * 8 + ph] + ad_p));
        }
        int kb = 0;
        // ---- fast path: full 16-edge double-batch, no predication ----
        for (; kb + 16 <= cnt; kb += 16) {
            int sA_[8]; float pA_[8];
            int sB_[8]; float pB_[8];
            #pragma unroll
            for (int j = 0; j < 8; ++j) {
                sA_[j] = __shfl(myS, kb + j);
                pA_[j] = __shfl(p8[j], kb + head);
            }
            uint2 rawA[8];
            #pragma unroll
            for (int j = 0; j < 8; ++j)
                rawA[j] = *reinterpret_cast<const uint2*>(
                    h1h + (size_t)sA_[j] * 256 + lane * 4);
            #pragma unroll
            for (int j = 0; j < 8; ++j) {
                sB_[j] = __shfl(myS, kb + 8 + j);
                pB_[j] = __shfl(p8[j], kb + 8 + head);
            }
            uint2 rawB[8];
            #pragma unroll
            for (int j = 0; j < 8; ++j)
                rawB[j] = *reinterpret_cast<const uint2*>(
                    h1h + (size_t)sB_[j] * 256 + lane * 4);
            #pragma unroll
            for (int j = 0; j < 8; ++j) {
                union { unsigned uu; __half2 h; } u0, u1;
                u0.uu = rawA[j].x; u1.uu = rawA[j].y;
                float2 f01 = __half22float2(u0.h);
                float2 f23 = __half22float2(u1.h);
                denom += pA_[j];
                a0 += pA_[j] * f01.x; a1 += pA_[j] * f01.y;
                a2 += pA_[j] * f23.x; a3 += pA_[j] * f23.y;
            }
            #pragma unroll
            for (int j = 0; j < 8; ++j) {
                union { unsigned uu; __half2 h; } u0, u1;
                u0.uu = rawB[j].x; u1.uu = rawB[j].y;
                float2 f01 = __half22float2(u0.h);
                float2 f23 = __half22float2(u1.h);
                denom += pB_[j];
                a0 += pB_[j] * f01.x; a1 += pB_[j] * f01.y;
                a2 += pB_[j] * f23.x; a3 += pB_[j] * f23.y;
            }
        }
        // ---- ragged tail: predicated batch-8 (p=0 pad, exact) ----
        for (; kb < cnt; kb += 8) {
            int sA_[8]; float pA_[8];
            #pragma unroll
            for (int j = 0; j < 8; ++j) {
                int k = kb + j;                      // wave-uniform
                int ks = k < 63 ? k : 63;
                sA_[j] = __shfl(myS, ks);            // convergent (clamped)
                float pv = __shfl(p8[j], kb + head); // convergent
                pA_[j] = (k < cnt) ? pv : 0.f;       // exact: +0 adds nothing
            }
            uint2 raw[8];
            #pragma unroll
            for (int j = 0; j < 8; ++j)
                raw[j] = *reinterpret_cast<const uint2*>(
                    h1h + (size_t)sA_[j] * 256 + lane * 4);
            #pragma unroll
            for (int j = 0; j < 8; ++j) {
                union { unsigned uu; __half2 h; } u0, u1;
                u0.uu = raw[j].x; u1.uu = raw[j].y;
                float2 f01 = __half22float2(u0.h);
                float2 f23 = __half22float2(u1.h);
                denom += pA_[j];
                a0 += pA_[j] * f01.x; a1 += pA_[j] * f01.y;
                a2 += pA_[j] * f23.x; a3 += pA_[j] * f23.y;
            }
        }
    }
    float inv = 1.f / (denom + 1e-16f);
    int c = lane * 4;
    float4 bv = *reinterpret_cast<const float4*>(&b1[c]);
    float r0 = a0 * inv + bv.x;
    float r1 = a1 * inv + bv.y;
    float r2 = a2 * inv + bv.z;
    float r3 = a3 * inv + bv.w;
    r0 = r0 > 0.f ? r0 : (__expf(r0) - 1.f);
    r1 = r1 > 0.f ? r1 : (__expf(r1) - 1.f);
    r2 = r2 > 0.f ? r2 : (__expf(r2) - 1.f);
    r3 = r3 > 0.f ? r3 : (__expf(r3) - 1.f);
    // ---- node2 tail: feat -> LDS (wave-private row; no barrier needed) ----
    float4 fv; fv.x = r0; fv.y = r1; fv.z = r2; fv.w = r3;
    *reinterpret_cast<float4*>(&feat_lds[wid * 256 + c]) = fv;
    int o = lane & 15, q = lane >> 4;
    const float* fl = &feat_lds[wid * 256 + q * 64];
    const float* w = w_lds + ((q >> 1) << 11) + ((q & 1) << 4) + o;  // + j*32
    float acc = 0.f;
    #pragma unroll 8
    for (int j = 0; j < 64; ++j)
        acc += fl[j] * w[j * 32];
    acc += __shfl_xor(acc, 16);
    acc += __shfl_xor(acc, 32);    // all lanes hold h2[d][o]
    if (lane < 16) h2h[d * 16 + o] = __float2half(acc);
    float ts = acc * att_s2[o], td = acc * att_d2[o];
    #pragma unroll
    for (int m = 1; m < 16; m <<= 1) {
        ts += __shfl_xor(ts, m);
        td += __shfl_xor(td, m);
    }
    if (lane == 0) { as2[d] = ts; ad2[d] = td; }
}

// K_agg2: one wave per dst. 16 edge-groups x 4 lanes owning 4 channels each.
__global__ void k_agg2(const __half* __restrict__ h2h, const float* __restrict__ as2,
                       const float* __restrict__ ad2, const float* __restrict__ b2,
                       const int* __restrict__ offs, const int* __restrict__ srcs,
                       float* __restrict__ out, int N) {
    int wid = threadIdx.x >> 6;
    int d = blockIdx.x * 4 + wid;
    if (d >= N) return;
    int lane = threadIdx.x & 63;
    int cl = lane & 3, eg = lane >> 2;
    float ad = ad2[d];
    int beg = offs[d], end = offs[d + 1];
    float denom = 0.f, a0 = 0.f, a1 = 0.f, a2 = 0.f, a3 = 0.f;
    for (int cb = beg; cb < end; cb += 64) {
        int idx = cb + lane;
        int myS = srcs[idx < end ? idx : end - 1];
        #pragma unroll
        for (int cc = 0; cc < 4; ++cc) {
            int s = __shfl(myS, cc * 16 + eg);   // convergent
            int epos2 = cb + cc * 16 + eg;
            if (epos2 < end) {
                float e = leaky02(as2[s] + ad);
                float p = __expf(e);
                denom += p;
                uint2 raw = *reinterpret_cast<const uint2*>(h2h + (size_t)s * 16 + cl * 4);
                union { unsigned u; __half2 h; } u0, u1;
                u0.u = raw.x; u1.u = raw.y;
                float2 f01 = __half22float2(u0.h);
                float2 f23 = __half22float2(u1.h);
                a0 += p * f01.x; a1 += p * f01.y; a2 += p * f23.x; a3 += p * f23.y;
            }
        }
    }
    #pragma unroll
    for (int m = 4; m < 64; m <<= 1) {
        denom += __shfl_xor(denom, m);
        a0 += __shfl_xor(a0, m);
        a1 += __shfl_xor(a1, m);
        a2 += __shfl_xor(a2, m);
        a3 += __shfl_xor(a3, m);
    }
    if (eg == 0) {
        float inv = 1.f / (denom + 1e-16f);
        int c = cl * 4;
        float4 r;
        r.x = a0 * inv + b2[c + 0];
        r.y = a1 * inv + b2[c + 1];
        r.z = a2 * inv + b2[c + 2];
        r.w = a3 * inv + b2[c + 3];
        *reinterpret_cast<float4*>(&out[d * 16 + c]) = r;
    }
}

extern "C" void kernel_launch(void* const* d_in, const int* in_sizes, int n_in,
                              void* d_out, int out_size, void* d_ws, size_t ws_size,
                              hipStream_t stream) {
    const float* x       = (const float*)d_in[0];
    const int*   ei      = (const int*)d_in[1];
    const float* W1      = (const float*)d_in[2];
    const float* att_s1  = (const float*)d_in[3];
    const float* att_d1  = (const float*)d_in[4];
    const float* b1      = (const float*)d_in[5];
    const float* W2      = (const float*)d_in[6];
    const float* att_s2  = (const float*)d_in[7];
    const float* att_d2  = (const float*)d_in[8];
    const float* b2      = (const float*)d_in[9];
    float* out = (float*)d_out;

    const int N = in_sizes[0] / 3;
    const int E = in_sizes[1] / 2;
    const int Etot = E + N;
    const int NB = (N + 1023) / 1024;  // scan blocks

    // carve workspace (16B aligned slices)
    char* w = (char*)d_ws;
    auto alloc = [&](size_t bytes) -> void* {
        void* p = (void*)w;
        w += (bytes + 15) & ~(size_t)15;
        return p;
    };
    int* counts_pad = (int*)alloc((size_t)N * CPAD * 4);   // 6.4 MB padded
    int* counts     = (int*)alloc((size_t)N * 4);
    int* offs       = (int*)alloc((size_t)(N + 1) * 4);
    int* epos       = (int*)alloc((size_t)E * 4);
    int* srcs       = (int*)alloc((size_t)Etot * 4);
    __half* h1h     = (__half*)alloc((size_t)N * 256 * 2);
    float* as1      = (float*)alloc((size_t)N * 8 * 4);
    float* ad1      = (float*)alloc((size_t)N * 8 * 4);
    __half* h2h     = (__half*)alloc((size_t)N * 16 * 2);
    float* as2      = (float*)alloc((size_t)N * 4);
    float* ad2      = (float*)alloc((size_t)N * 4);
    (void)ws_size; (void)n_in; (void)out_size;

    const int B = 256;
    const int NBc = (E + B - 1) / B;        // count blocks (FIRST in k_prep)
    const int NB1 = (N + 3) / 4;            // node1 blocks

    hipMemsetAsync(counts_pad, 0, (size_t)N * CPAD * 4, stream);
    hipLaunchKernelGGL(k_prep, dim3(NBc + NB1), dim3(B), 0, stream,
                       x, W1, att_s1, att_d1, h1h, as1, ad1, ei, counts_pad, epos,
                       N, E, NBc);
    hipLaunchKernelGGL(k_compact, dim3((N + B - 1) / B), dim3(B), 0, stream,
                       counts_pad, counts, N);
    hipLaunchKernelGGL(k_offs2, dim3(NB), dim3(B), 0, stream, counts, offs, srcs, N);
    hipLaunchKernelGGL(k_scatter, dim3((E + B - 1) / B), dim3(B), 0, stream,
                       ei, offs, epos, srcs, E);
    hipLaunchKernelGGL(k_agg1n2, dim3((N + 3) / 4), dim3(B), 0, stream,
                       h1h, as1, ad1, b1, W2, att_s2, att_d2, offs, srcs,
                       h2h, as2, ad2, N);
    hipLaunchKernelGGL(k_agg2, dim3((N + 3) / 4), dim3(B), 0, stream,
                       h2h, as2, ad2, b2, offs, srcs, out, N);
}

// Round 19
// 178.865 us; speedup vs baseline: 1.3088x; 1.3088x over previous
//
#include <hip/hip_runtime.h>
#include <hip/hip_bf16.h>
#include <hip/hip_fp16.h>
#include <math.h>

__device__ __forceinline__ float leaky02(float x) { return x > 0.f ? x : 0.2f * x; }

#define CPAD 32   // counters padded to one 128B line each (R16: fixed atomic serialization)

// K_prep: fat kernel. Blocks [0,NBc): edge dst count+rank (returning atomic
// on line-padded counters). Blocks [NBc,...): node1 transform.
__global__ void k_prep(const float* __restrict__ x, const float* __restrict__ W1,
                       const float* __restrict__ att_s, const float* __restrict__ att_d,
                       __half* __restrict__ h1h, float* __restrict__ as1,
                       float* __restrict__ ad1,
                       const int* __restrict__ ei, int* __restrict__ counts_pad,
                       int* __restrict__ epos,
                       int N, int E, int NBc) {
    int b = blockIdx.x;
    if (b < NBc) {
        int t = b * blockDim.x + threadIdx.x;
        if (t < E) {
            int d = ei[E + t];
            epos[t] = atomicAdd(&counts_pad[(size_t)d * CPAD], 1);
        }
        return;
    }
    int nb = b - NBc;
    int wid = threadIdx.x >> 6;
    int n = nb * 4 + wid;
    if (n >= N) return;
    int lane = threadIdx.x & 63;
    int c = lane * 4;
    float x0 = x[n * 3 + 0], x1 = x[n * 3 + 1], x2 = x[n * 3 + 2];
    float4 w0 = *reinterpret_cast<const float4*>(&W1[c]);
    float4 w1 = *reinterpret_cast<const float4*>(&W1[256 + c]);
    float4 w2 = *reinterpret_cast<const float4*>(&W1[512 + c]);
    float h0 = x0 * w0.x + x1 * w1.x + x2 * w2.x;
    float h1_ = x0 * w0.y + x1 * w1.y + x2 * w2.y;
    float h2_ = x0 * w0.z + x1 * w1.z + x2 * w2.z;
    float h3 = x0 * w0.w + x1 * w1.w + x2 * w2.w;
    union { __half2 h[2]; uint2 u; } pk;
    pk.h[0] = __floats2half2_rn(h0, h1_);
    pk.h[1] = __floats2half2_rn(h2_, h3);
    *reinterpret_cast<uint2*>(h1h + (size_t)n * 256 + c) = pk.u;
    float4 as = *reinterpret_cast<const float4*>(&att_s[c]);
    float4 ad = *reinterpret_cast<const float4*>(&att_d[c]);
    float vs = h0 * as.x + h1_ * as.y + h2_ * as.z + h3 * as.w;
    float vd = h0 * ad.x + h1_ * ad.y + h2_ * ad.z + h3 * ad.w;
    #pragma unroll
    for (int m = 1; m < 8; m <<= 1) {
        vs += __shfl_xor(vs, m);
        vd += __shfl_xor(vd, m);
    }
    if ((lane & 7) == 0) {
        as1[n * 8 + (lane >> 3)] = vs;
        ad1[n * 8 + (lane >> 3)] = vd;
    }
}

// K_compact: densify padded counters (one thread per node).
__global__ void k_compact(const int* __restrict__ counts_pad,
                          int* __restrict__ counts, int N) {
    int i = blockIdx.x * blockDim.x + threadIdx.x;
    if (i < N) counts[i] = counts_pad[(size_t)i * CPAD];
}

// K_offs2: per-block offsets; block computes its own prefix (dense counts).
// Also places the self-loop at the LAST slot of each segment.
__global__ void k_offs2(const int* __restrict__ counts,
                        int* __restrict__ offs, int* __restrict__ srcs, int N) {
    __shared__ int red[4];
    __shared__ int wsum[4];
    int b = blockIdx.x;
    int t = threadIdx.x;
    int lane = t & 63, wid = t >> 6;
    int lim = b << 10;
    int s = 0;
    for (int i = t * 4; i < lim; i += 1024) {
        int4 v = *reinterpret_cast<const int4*>(&counts[i]);
        s += v.x + v.y + v.z + v.w + 4;
    }
    #pragma unroll
    for (int m = 1; m < 64; m <<= 1) s += __shfl_xor(s, m);
    if (lane == 0) red[wid] = s;
    __syncthreads();
    int P = red[0] + red[1] + red[2] + red[3];
    int i0 = (b << 10) + t * 4;
    int c0 = 0, c1 = 0, c2 = 0, c3 = 0;
    if (i0 + 3 < N) {
        int4 cv = *reinterpret_cast<const int4*>(&counts[i0]);
        c0 = cv.x + 1; c1 = cv.y + 1; c2 = cv.z + 1; c3 = cv.w + 1;
    } else {
        if (i0 + 0 < N) c0 = counts[i0 + 0] + 1;
        if (i0 + 1 < N) c1 = counts[i0 + 1] + 1;
        if (i0 + 2 < N) c2 = counts[i0 + 2] + 1;
        if (i0 + 3 < N) c3 = counts[i0 + 3] + 1;
    }
    int tsum = c0 + c1 + c2 + c3;
    int incl = tsum;
    #pragma unroll
    for (int off = 1; off < 64; off <<= 1) {
        int tv = __shfl_up(incl, off);
        if (lane >= off) incl += tv;
    }
    if (lane == 63) wsum[wid] = incl;
    __syncthreads();
    int woff = 0;
    for (int w = 0; w < wid; ++w) woff += wsum[w];
    int base = P + woff + incl - tsum;
    int p0 = base;
    int p1 = p0 + c0;
    int p2 = p1 + c1;
    int p3 = p2 + c2;
    int p4 = p3 + c3;
    if (i0 + 0 < N) { offs[i0 + 1] = p1; srcs[p1 - 1] = i0 + 0; }
    if (i0 + 1 < N) { offs[i0 + 2] = p2; srcs[p2 - 1] = i0 + 1; }
    if (i0 + 2 < N) { offs[i0 + 3] = p3; srcs[p3 - 1] = i0 + 2; }
    if (i0 + 3 < N) { offs[i0 + 4] = p4; srcs[p4 - 1] = i0 + 3; }
    if (b == 0 && t == 0) offs[0] = 0;
}

// K_scatter: E edges only; position precomputed (epos); no atomics.
__global__ void k_scatter(const int* __restrict__ ei, const int* __restrict__ offs,
                          const int* __restrict__ epos, int* __restrict__ srcs, int E) {
    int t = blockIdx.x * blockDim.x + threadIdx.x;
    if (t < E) {
        int s = ei[t], d = ei[E + t];
        srcs[offs[d] + epos[t]] = s;
    }
}

// K_agg1n2: agg1 + node2 tail via LDS. R16/R17-proven 8-deep batch:
// 8 unconditional uint2 loads in flight (VGPR 32, no spill -- R17 lesson:
// 16-deep exceeded the (256,8) 64-VGPR cap and spilled, WRITE_SIZE 3->211MB).
// p=0 tail pad (exact); convergent shfls; static indexing (rule 20).
// W2 staging dst-linear (conflict-free, R13); feat_lds linear (R12);
// LDS 20480 B = exactly 8 blocks/CU (R11).
__global__ void __launch_bounds__(256, 8)
k_agg1n2(const __half* __restrict__ h1h, const float* __restrict__ as1,
         const float* __restrict__ ad1, const float* __restrict__ b1,
         const float* __restrict__ W2, const float* __restrict__ att_s2,
         const float* __restrict__ att_d2,
         const int* __restrict__ offs, const int* __restrict__ srcs,
         __half* __restrict__ h2h, float* __restrict__ as2,
         float* __restrict__ ad2, int N) {
    __shared__ float w_lds[4096];
    __shared__ float feat_lds[1024];
    int t = threadIdx.x;
    #pragma unroll
    for (int p = 0; p < 4; ++p) {
        int dw = p * 1024 + t * 4;
        int hi = dw >> 11;
        int r = dw & 2047;
        int row = r >> 5;
        int rem = r & 31;
        int half = rem >> 4;
        int o = rem & 15;
        int k = (hi << 7) | (half << 6) | row;
        *reinterpret_cast<float4*>(&w_lds[dw]) =
            *reinterpret_cast<const float4*>(&W2[k * 16 + o]);
    }
    __syncthreads();

    int wid = t >> 6;
    int d = blockIdx.x * 4 + wid;
    if (d >= N) return;
    int lane = t & 63;
    int head = lane >> 3;
    int po = lane >> 3;
    int ph = lane & 7;
    float ad_p = ad1[d * 8 + ph];
    int beg = offs[d], end = offs[d + 1];
    float denom = 0.f, a0 = 0.f, a1 = 0.f, a2 = 0.f, a3 = 0.f;
    for (int cb = beg; cb < end; cb += 64) {
        int idx = cb + lane;
        int myS = srcs[idx < end ? idx : end - 1];
        int cnt = min(64, end - cb);   // wave-uniform
        float p8[8];
        #pragma unroll
        for (int j = 0; j < 8; ++j) {
            int s = __shfl(myS, po * 8 + j);
            p8[j] = __expf(leaky02(as1[s * 8 + ph] + ad_p));
        }
        for (int kb = 0; kb < cnt; kb += 8) {
            int sA[8];
            float pA[8];
            #pragma unroll
            for (int j = 0; j < 8; ++j) {
                int k = kb + j;                      // wave-uniform
                int ks = k < 63 ? k : 63;
                sA[j] = __shfl(myS, ks);             // convergent (clamped)
                float pv = __shfl(p8[j], kb + head); // convergent
                pA[j] = (k < cnt) ? pv : 0.f;        // exact: +0 adds nothing
            }
            uint2 raw[8];
            #pragma unroll
            for (int j = 0; j < 8; ++j)
                raw[j] = *reinterpret_cast<const uint2*>(
                    h1h + (size_t)sA[j] * 256 + lane * 4);
            #pragma unroll
            for (int j = 0; j < 8; ++j) {
                union { unsigned uu; __half2 h; } u0, u1;
                u0.uu = raw[j].x; u1.uu = raw[j].y;
                float2 f01 = __half22float2(u0.h);
                float2 f23 = __half22float2(u1.h);
                denom += pA[j];
                a0 += pA[j] * f01.x; a1 += pA[j] * f01.y;
                a2 += pA[j] * f23.x; a3 += pA[j] * f23.y;
            }
        }
    }
    float inv = 1.f / (denom + 1e-16f);
    int c = lane * 4;
    float4 bv = *reinterpret_cast<const float4*>(&b1[c]);
    float r0 = a0 * inv + bv.x;
    float r1 = a1 * inv + bv.y;
    float r2 = a2 * inv + bv.z;
    float r3 = a3 * inv + bv.w;
    r0 = r0 > 0.f ? r0 : (__expf(r0) - 1.f);
    r1 = r1 > 0.f ? r1 : (__expf(r1) - 1.f);
    r2 = r2 > 0.f ? r2 : (__expf(r2) - 1.f);
    r3 = r3 > 0.f ? r3 : (__expf(r3) - 1.f);
    // ---- node2 tail: feat -> LDS (wave-private row; no barrier needed) ----
    float4 fv; fv.x = r0; fv.y = r1; fv.z = r2; fv.w = r3;
    *reinterpret_cast<float4*>(&feat_lds[wid * 256 + c]) = fv;
    int o = lane & 15, q = lane >> 4;
    const float* fl = &feat_lds[wid * 256 + q * 64];
    const float* w = w_lds + ((q >> 1) << 11) + ((q & 1) << 4) + o;  // + j*32
    float acc = 0.f;
    #pragma unroll 8
    for (int j = 0; j < 64; ++j)
        acc += fl[j] * w[j * 32];
    acc += __shfl_xor(acc, 16);
    acc += __shfl_xor(acc, 32);    // all lanes hold h2[d][o]
    if (lane < 16) h2h[d * 16 + o] = __float2half(acc);
    float ts = acc * att_s2[o], td = acc * att_d2[o];
    #pragma unroll
    for (int m = 1; m < 16; m <<= 1) {
        ts += __shfl_xor(ts, m);
        td += __shfl_xor(td, m);
    }
    if (lane == 0) { as2[d] = ts; ad2[d] = td; }
}

// K_agg2: one wave per dst. 16 edge-groups x 4 lanes owning 4 channels each.
// Batched-MLP (R15 pattern): all 4 (s,ok) computed unconditionally per chunk
// (clamped src -> valid addr; convergent shfls), then 4 unconditional h2h
// loads + as2 loads in flight; p = ok ? exp(..) : 0 (exact).
__global__ void k_agg2(const __half* __restrict__ h2h, const float* __restrict__ as2,
                       const float* __restrict__ ad2, const float* __restrict__ b2,
                       const int* __restrict__ offs, const int* __restrict__ srcs,
                       float* __restrict__ out, int N) {
    int wid = threadIdx.x >> 6;
    int d = blockIdx.x * 4 + wid;
    if (d >= N) return;
    int lane = threadIdx.x & 63;
    int cl = lane & 3, eg = lane >> 2;
    float ad = ad2[d];
    int beg = offs[d], end = offs[d + 1];
    float denom = 0.f, a0 = 0.f, a1 = 0.f, a2 = 0.f, a3 = 0.f;
    for (int cb = beg; cb < end; cb += 64) {
        int idx = cb + lane;
        int myS = srcs[idx < end ? idx : end - 1];
        int sA[4];
        bool ok[4];
        #pragma unroll
        for (int cc = 0; cc < 4; ++cc) {
            sA[cc] = __shfl(myS, cc * 16 + eg);          // convergent (clamped)
            ok[cc] = (cb + cc * 16 + eg) < end;
        }
        float av[4];
        uint2 raw[4];
        #pragma unroll
        for (int cc = 0; cc < 4; ++cc) {
            av[cc] = as2[sA[cc]];
            raw[cc] = *reinterpret_cast<const uint2*>(h2h + (size_t)sA[cc] * 16 + cl * 4);
        }
        #pragma unroll
        for (int cc = 0; cc < 4; ++cc) {
            float p = ok[cc] ? __expf(leaky02(av[cc] + ad)) : 0.f;
            union { unsigned u; __half2 h; } u0, u1;
            u0.u = raw[cc].x; u1.u = raw[cc].y;
            float2 f01 = __half22float2(u0.h);
            float2 f23 = __half22float2(u1.h);
            denom += p;
            a0 += p * f01.x; a1 += p * f01.y; a2 += p * f23.x; a3 += p * f23.y;
        }
    }
    #pragma unroll
    for (int m = 4; m < 64; m <<= 1) {
        denom += __shfl_xor(denom, m);
        a0 += __shfl_xor(a0, m);
        a1 += __shfl_xor(a1, m);
        a2 += __shfl_xor(a2, m);
        a3 += __shfl_xor(a3, m);
    }
    if (eg == 0) {
        float inv = 1.f / (denom + 1e-16f);
        int c = cl * 4;
        float4 r;
        r.x = a0 * inv + b2[c + 0];
        r.y = a1 * inv + b2[c + 1];
        r.z = a2 * inv + b2[c + 2];
        r.w = a3 * inv + b2[c + 3];
        *reinterpret_cast<float4*>(&out[d * 16 + c]) = r;
    }
}

extern "C" void kernel_launch(void* const* d_in, const int* in_sizes, int n_in,
                              void* d_out, int out_size, void* d_ws, size_t ws_size,
                              hipStream_t stream) {
    const float* x       = (const float*)d_in[0];
    const int*   ei      = (const int*)d_in[1];
    const float* W1      = (const float*)d_in[2];
    const float* att_s1  = (const float*)d_in[3];
    const float* att_d1  = (const float*)d_in[4];
    const float* b1      = (const float*)d_in[5];
    const float* W2      = (const float*)d_in[6];
    const float* att_s2  = (const float*)d_in[7];
    const float* att_d2  = (const float*)d_in[8];
    const float* b2      = (const float*)d_in[9];
    float* out = (float*)d_out;

    const int N = in_sizes[0] / 3;
    const int E = in_sizes[1] / 2;
    const int Etot = E + N;
    const int NB = (N + 1023) / 1024;  // scan blocks

    // carve workspace (16B aligned slices)
    char* w = (char*)d_ws;
    auto alloc = [&](size_t bytes) -> void* {
        void* p = (void*)w;
        w += (bytes + 15) & ~(size_t)15;
        return p;
    };
    int* counts_pad = (int*)alloc((size_t)N * CPAD * 4);   // 6.4 MB padded
    int* counts     = (int*)alloc((size_t)N * 4);
    int* offs       = (int*)alloc((size_t)(N + 1) * 4);
    int* epos       = (int*)alloc((size_t)E * 4);
    int* srcs       = (int*)alloc((size_t)Etot * 4);
    __half* h1h     = (__half*)alloc((size_t)N * 256 * 2);
    float* as1      = (float*)alloc((size_t)N * 8 * 4);
    float* ad1      = (float*)alloc((size_t)N * 8 * 4);
    __half* h2h     = (__half*)alloc((size_t)N * 16 * 2);
    float* as2      = (float*)alloc((size_t)N * 4);
    float* ad2      = (float*)alloc((size_t)N * 4);
    (void)ws_size; (void)n_in; (void)out_size;

    const int B = 256;
    const int NBc = (E + B - 1) / B;        // count blocks (FIRST in k_prep)
    const int NB1 = (N + 3) / 4;            // node1 blocks

    hipMemsetAsync(counts_pad, 0, (size_t)N * CPAD * 4, stream);
    hipLaunchKernelGGL(k_prep, dim3(NBc + NB1), dim3(B), 0, stream,
                       x, W1, att_s1, att_d1, h1h, as1, ad1, ei, counts_pad, epos,
                       N, E, NBc);
    hipLaunchKernelGGL(k_compact, dim3((N + B - 1) / B), dim3(B), 0, stream,
                       counts_pad, counts, N);
    hipLaunchKernelGGL(k_offs2, dim3(NB), dim3(B), 0, stream, counts, offs, srcs, N);
    hipLaunchKernelGGL(k_scatter, dim3((E + B - 1) / B), dim3(B), 0, stream,
                       ei, offs, epos, srcs, E);
    hipLaunchKernelGGL(k_agg1n2, dim3((N + 3) / 4), dim3(B), 0, stream,
                       h1h, as1, ad1, b1, W2, att_s2, att_d2, offs, srcs,
                       h2h, as2, ad2, N);
    hipLaunchKernelGGL(k_agg2, dim3((N + 3) / 4), dim3(B), 0, stream,
                       h2h, as2, ad2, b2, offs, srcs, out, N);
}